// Round 4
// baseline (94.343 us; speedup 1.0000x reference)
//
#include <hip/hip_runtime.h>
#include <hip/hip_cooperative_groups.h>
#include <math.h>

namespace cg = cooperative_groups;

// Van Rossum loss, single fused cooperative kernel.
//   f[t] = r*f[t-1] + c*x[t],  x = spike - target
//   loss = mean_b sum_{t,n} f^2
// Chunked scan decomposition (NCHUNK=32 chunks of LCHUNK=32):
//   phase1 (256 blocks): per (b,chunk,q-float4): local scan l, E=l[end],
//     B = sum r^{k+1} l[k], C = sum l[k]^2 (block-reduced to wsC[block])
//   grid.sync
//   phase2 (blocks 0..31): carry F across chunks:
//     sum f^2 = A*F^2 + 2*F*B + C,  F <- r^L*F + E   -> wsP[b]
//   grid.sync
//   block 0: total = sum(wsC) + sum(wsP); out[0] = total/B  (plain store, no memset)

#define B_DIM 32
#define T_DIM 1024
#define N_DIM 256
#define NCHUNK 32
#define LCHUNK 32               // T_DIM / NCHUNK
#define NQ 64                   // N_DIM / 4

__global__ __launch_bounds__(256) void vr_fused(
    const float* __restrict__ spike, const float* __restrict__ target,
    float4* __restrict__ wsE, float4* __restrict__ wsB,
    float* __restrict__ wsC, float* __restrict__ wsP,
    float* __restrict__ out,
    float r, float cp, float rL, float A, float invB)
{
    cg::grid_group grid = cg::this_grid();
    __shared__ float red[4];
    int tid = threadIdx.x;
    int lane = tid & 63, wid = tid >> 6;
    int g = blockIdx.x * 256 + tid;

    // ---------------- phase 1: per-chunk local scans ----------------
    {
        int q     = g & (NQ - 1);
        int bc    = g >> 6;
        int chunk = bc & (NCHUNK - 1);
        int b     = bc >> 5;
        int t0    = chunk * LCHUNK;

        size_t base = ((size_t)(b * T_DIM + t0) * N_DIM) + ((size_t)q << 2);
        const float4* sp = reinterpret_cast<const float4*>(spike + base);
        const float4* tg = reinterpret_cast<const float4*>(target + base);

        float4 l  = make_float4(0.f, 0.f, 0.f, 0.f);
        float4 Bs = make_float4(0.f, 0.f, 0.f, 0.f);
        float4 Cs = make_float4(0.f, 0.f, 0.f, 0.f);
        float w = r;
        #pragma unroll 8
        for (int k = 0; k < LCHUNK; ++k) {
            float4 s = sp[k * (N_DIM / 4)];
            float4 t = tg[k * (N_DIM / 4)];
            float xx = s.x - t.x, xy = s.y - t.y, xz = s.z - t.z, xw = s.w - t.w;
            l.x = fmaf(r, l.x, cp * xx);
            l.y = fmaf(r, l.y, cp * xy);
            l.z = fmaf(r, l.z, cp * xz);
            l.w = fmaf(r, l.w, cp * xw);
            Bs.x = fmaf(w, l.x, Bs.x);
            Bs.y = fmaf(w, l.y, Bs.y);
            Bs.z = fmaf(w, l.z, Bs.z);
            Bs.w = fmaf(w, l.w, Bs.w);
            Cs.x = fmaf(l.x, l.x, Cs.x);
            Cs.y = fmaf(l.y, l.y, Cs.y);
            Cs.z = fmaf(l.z, l.z, Cs.z);
            Cs.w = fmaf(l.w, l.w, Cs.w);
            w *= r;
        }
        int o = (chunk * B_DIM + b) * NQ + q;
        wsE[o] = l;
        wsB[o] = Bs;

        float c = (Cs.x + Cs.y) + (Cs.z + Cs.w);
        #pragma unroll
        for (int off = 32; off > 0; off >>= 1) c += __shfl_down(c, off);
        if (lane == 0) red[wid] = c;
        __syncthreads();
        if (tid == 0) wsC[blockIdx.x] = (red[0] + red[1]) + (red[2] + red[3]);
    }

    grid.sync();

    // ---------------- phase 2: carry combine (32 blocks, 1 wave each) ----------------
    if (blockIdx.x < B_DIM && tid < NQ) {
        int b = blockIdx.x, q = tid;
        float4 F = make_float4(0.f, 0.f, 0.f, 0.f);
        float acc = 0.f;
        #pragma unroll 8
        for (int chunk = 0; chunk < NCHUNK; ++chunk) {
            int o = (chunk * B_DIM + b) * NQ + q;
            float4 E  = wsE[o];
            float4 Bv = wsB[o];
            acc += A * ((F.x * F.x + F.y * F.y) + (F.z * F.z + F.w * F.w))
                 + 2.f * ((F.x * Bv.x + F.y * Bv.y) + (F.z * Bv.z + F.w * Bv.w));
            F.x = fmaf(rL, F.x, E.x);
            F.y = fmaf(rL, F.y, E.y);
            F.z = fmaf(rL, F.z, E.z);
            F.w = fmaf(rL, F.w, E.w);
        }
        #pragma unroll
        for (int off = 32; off > 0; off >>= 1) acc += __shfl_down(acc, off);
        if (q == 0) wsP[b] = acc;
    }

    grid.sync();

    // ---------------- final: block 0 reduces 256 + 32 partials ----------------
    if (blockIdx.x == 0) {
        float v = wsC[tid];
        if (tid < B_DIM) v += wsP[tid];
        #pragma unroll
        for (int off = 32; off > 0; off >>= 1) v += __shfl_down(v, off);
        if (lane == 0) red[wid] = v;
        __syncthreads();
        if (tid == 0) out[0] = ((red[0] + red[1]) + (red[2] + red[3])) * invB;
    }
}

extern "C" void kernel_launch(void* const* d_in, const int* in_sizes, int n_in,
                              void* d_out, int out_size, void* d_ws, size_t ws_size,
                              hipStream_t stream)
{
    (void)in_sizes; (void)n_in; (void)ws_size; (void)out_size;
    const float* spike  = (const float*)d_in[0];
    const float* target = (const float*)d_in[1];
    float* out = (float*)d_out;

    float4* wsE = (float4*)d_ws;                                  // 1 MiB
    float4* wsB = wsE + (size_t)NCHUNK * B_DIM * NQ;              // 1 MiB
    float*  wsC = (float*)(wsB + (size_t)NCHUNK * B_DIM * NQ);    // 256 floats
    float*  wsP = wsC + 256;                                      // 32 floats

    const double tau = 20.0, dt = 1.0;
    const double rd = exp(dt / tau);
    const double r2 = rd * rd;
    float r    = (float)rd;
    float cp   = (float)(exp(-(double)(T_DIM - 1) * dt / tau) / tau);
    float rL   = (float)exp((double)LCHUNK * dt / tau);
    float A    = (float)(r2 * (pow(r2, (double)LCHUNK) - 1.0) / (r2 - 1.0));
    float invB = 1.0f / (float)B_DIM;

    void* args[] = { (void*)&spike, (void*)&target, (void*)&wsE, (void*)&wsB,
                     (void*)&wsC, (void*)&wsP, (void*)&out,
                     (void*)&r, (void*)&cp, (void*)&rL, (void*)&A, (void*)&invB };
    hipLaunchCooperativeKernel((const void*)vr_fused, dim3(256), dim3(256),
                               args, 0, stream);
}

// Round 5
// 22.114 us; speedup vs baseline: 4.2663x; 4.2663x over previous
//
#include <hip/hip_runtime.h>
#include <math.h>

// Van Rossum loss, 2-dispatch chunked-scan version.
//   f[t] = r*f[t-1] + c*x[t],  x = spike - target
//   loss = mean_b sum_{t,n} f^2
// pass1 (256 blocks): per (b,chunk,q): local scan l over LCHUNK=32 steps;
//   E = l[end], B = sum_k r^{k+1} l[k]  -> wsE/wsB (plain stores)
//   C = sum_k l[k]^2 block-reduced     -> wsC[block] (plain store)
//   block 0 zeroes wsAcc/wsCnt for this replay (visible at dispatch boundary).
// pass2 (32 blocks, 1 wave): carry F across chunks for batch b:
//   sum f^2 += A*F^2 + 2*F*B (+C partials), F <- r^L*F + E
//   combine across blocks via device-scope atomicAdd + ticket; last block
//   writes out[0] = total/B  (no memset dispatch needed).

#define B_DIM 32
#define T_DIM 1024
#define N_DIM 256
#define NCHUNK 32
#define LCHUNK 32               // T_DIM / NCHUNK
#define NQ 64                   // N_DIM / 4

__global__ __launch_bounds__(256) void vr_pass1(
    const float* __restrict__ spike, const float* __restrict__ target,
    float4* __restrict__ wsE, float4* __restrict__ wsB,
    float* __restrict__ wsC, float* __restrict__ wsAcc, unsigned* __restrict__ wsCnt,
    float r, float cp)
{
    int tid = threadIdx.x;
    if (blockIdx.x == 0 && tid == 0) { wsAcc[0] = 0.f; wsCnt[0] = 0u; }

    int g = blockIdx.x * 256 + tid;           // ((b*NCHUNK + chunk) * NQ) + q
    int q     = g & (NQ - 1);
    int bc    = g >> 6;
    int chunk = bc & (NCHUNK - 1);
    int b     = bc >> 5;
    int t0    = chunk * LCHUNK;

    size_t base = ((size_t)(b * T_DIM + t0) * N_DIM) + ((size_t)q << 2);
    const float4* sp = reinterpret_cast<const float4*>(spike + base);
    const float4* tg = reinterpret_cast<const float4*>(target + base);

    float4 l  = make_float4(0.f, 0.f, 0.f, 0.f);
    float4 Bs = make_float4(0.f, 0.f, 0.f, 0.f);
    float4 Cs = make_float4(0.f, 0.f, 0.f, 0.f);
    float w = r;
    #pragma unroll 8
    for (int k = 0; k < LCHUNK; ++k) {
        float4 s = sp[k * (N_DIM / 4)];
        float4 t = tg[k * (N_DIM / 4)];
        float xx = s.x - t.x, xy = s.y - t.y, xz = s.z - t.z, xw = s.w - t.w;
        l.x = fmaf(r, l.x, cp * xx);
        l.y = fmaf(r, l.y, cp * xy);
        l.z = fmaf(r, l.z, cp * xz);
        l.w = fmaf(r, l.w, cp * xw);
        Bs.x = fmaf(w, l.x, Bs.x);
        Bs.y = fmaf(w, l.y, Bs.y);
        Bs.z = fmaf(w, l.z, Bs.z);
        Bs.w = fmaf(w, l.w, Bs.w);
        Cs.x = fmaf(l.x, l.x, Cs.x);
        Cs.y = fmaf(l.y, l.y, Cs.y);
        Cs.z = fmaf(l.z, l.z, Cs.z);
        Cs.w = fmaf(l.w, l.w, Cs.w);
        w *= r;
    }
    int o = (chunk * B_DIM + b) * NQ + q;
    wsE[o] = l;
    wsB[o] = Bs;

    // per-block C partial (plain store; combined in pass2)
    float c = (Cs.x + Cs.y) + (Cs.z + Cs.w);
    #pragma unroll
    for (int off = 32; off > 0; off >>= 1) c += __shfl_down(c, off);
    __shared__ float red[4];
    int lane = tid & 63, wid = tid >> 6;
    if (lane == 0) red[wid] = c;
    __syncthreads();
    if (tid == 0) wsC[blockIdx.x] = (red[0] + red[1]) + (red[2] + red[3]);
}

__global__ __launch_bounds__(64) void vr_pass2(
    const float4* __restrict__ wsE, const float4* __restrict__ wsB,
    const float* __restrict__ wsC, float* __restrict__ wsAcc,
    unsigned* __restrict__ wsCnt, float* __restrict__ out,
    float rL, float A, float invB)
{
    int b = blockIdx.x;          // 0..31
    int q = threadIdx.x;         // 0..63

    float4 F = make_float4(0.f, 0.f, 0.f, 0.f);
    float acc = 0.f;
    #pragma unroll 8
    for (int chunk = 0; chunk < NCHUNK; ++chunk) {
        int o = (chunk * B_DIM + b) * NQ + q;
        float4 E  = wsE[o];
        float4 Bv = wsB[o];
        acc += A * ((F.x * F.x + F.y * F.y) + (F.z * F.z + F.w * F.w))
             + 2.f * ((F.x * Bv.x + F.y * Bv.y) + (F.z * Bv.z + F.w * Bv.w));
        F.x = fmaf(rL, F.x, E.x);
        F.y = fmaf(rL, F.y, E.y);
        F.z = fmaf(rL, F.z, E.z);
        F.w = fmaf(rL, F.w, E.w);
    }
    // fold this batch's 8 pass1 C-partials (pass1 block x covers batch x>>3)
    if (q < 8) acc += wsC[b * 8 + q];

    #pragma unroll
    for (int off = 32; off > 0; off >>= 1) acc += __shfl_down(acc, off);

    if (q == 0) {
        atomicAdd(wsAcc, acc);
        __threadfence();
        unsigned old = atomicAdd(wsCnt, 1u);
        if (old == 31u) {
            float total = atomicAdd(wsAcc, 0.0f);  // returns current full sum
            out[0] = total * invB;
        }
    }
}

extern "C" void kernel_launch(void* const* d_in, const int* in_sizes, int n_in,
                              void* d_out, int out_size, void* d_ws, size_t ws_size,
                              hipStream_t stream)
{
    (void)in_sizes; (void)n_in; (void)ws_size; (void)out_size;
    const float* spike  = (const float*)d_in[0];
    const float* target = (const float*)d_in[1];
    float* out = (float*)d_out;

    float4*   wsE   = (float4*)d_ws;                                  // 1 MiB
    float4*   wsB   = wsE + (size_t)NCHUNK * B_DIM * NQ;              // 1 MiB
    float*    wsC   = (float*)(wsB + (size_t)NCHUNK * B_DIM * NQ);    // 256 floats
    float*    wsAcc = wsC + 256;
    unsigned* wsCnt = (unsigned*)(wsAcc + 1);

    const double tau = 20.0, dt = 1.0;
    const double rd = exp(dt / tau);
    const double r2 = rd * rd;
    float r    = (float)rd;
    float cp   = (float)(exp(-(double)(T_DIM - 1) * dt / tau) / tau);
    float rL   = (float)exp((double)LCHUNK * dt / tau);
    float A    = (float)(r2 * (pow(r2, (double)LCHUNK) - 1.0) / (r2 - 1.0));
    float invB = 1.0f / (float)B_DIM;

    hipLaunchKernelGGL(vr_pass1, dim3((B_DIM * NCHUNK * NQ) / 256), dim3(256), 0, stream,
                       spike, target, wsE, wsB, wsC, wsAcc, wsCnt, r, cp);
    hipLaunchKernelGGL(vr_pass2, dim3(B_DIM), dim3(64), 0, stream,
                       wsE, wsB, wsC, wsAcc, wsCnt, out, rL, A, invB);
}